// Round 9
// baseline (42.435 us; speedup 1.0000x reference)
//
#include <hip/hip_runtime.h>

#define N_TOTAL 8192
#define B_HALF  4096
#define D_DIM   256
#define BM      256                   // rows per block (A LDS-resident)
#define CSPLIT  8
#define COLS_PER_SPLIT 1024
#define NTILE   8                     // 128-col B tiles per block

typedef __attribute__((ext_vector_type(4))) float f32x4;
typedef __attribute__((ext_vector_type(2))) long  long2_t;   // 16 B = 2 fp8 MFMA frags

// async global->LDS, 16B per lane (dest = wave-uniform base + lane*16)
#define GLOAD16(src, dst) __builtin_amdgcn_global_load_lds( \
    (const __attribute__((address_space(1))) unsigned int*)(src), \
    (__attribute__((address_space(3))) unsigned int*)(dst), 16, 0, 0)

// ---------------------------------------------------------------------------
// Kernel 1: fused normalize + positive-pair sim.  One WAVE per pair i.
// Writes zn8 in PERMUTED-K fp8: row byte p(k) = kgrp(k)*64 + ks(k)*8 + k%8
// (ks = k/32, kgrp = (k%32)/8) -> each lane's MFMA frags contiguous 16B cells.
// Rows scaled by sqrt(2) so fp8 dot = 2*cos = s directly.  pos in fp32.
// ---------------------------------------------------------------------------
__global__ __launch_bounds__(256) void nrmpos_kernel(const float* __restrict__ z1,
                                                     const float* __restrict__ z2,
                                                     unsigned char* __restrict__ zn8,
                                                     float* __restrict__ pos) {
    int i    = (blockIdx.x * 256 + threadIdx.x) >> 6;   // pair 0..4095
    int lane = threadIdx.x & 63;
    float4 a = reinterpret_cast<const float4*>(z1 + (size_t)i * D_DIM)[lane];
    float4 b = reinterpret_cast<const float4*>(z2 + (size_t)i * D_DIM)[lane];
    float ssa = a.x * a.x + a.y * a.y + a.z * a.z + a.w * a.w;
    float ssb = b.x * b.x + b.y * b.y + b.z * b.z + b.w * b.w;
    float dab = a.x * b.x + a.y * b.y + a.z * b.z + a.w * b.w;
#pragma unroll
    for (int m = 32; m >= 1; m >>= 1) {
        ssa += __shfl_xor(ssa, m);
        ssb += __shfl_xor(ssb, m);
        dab += __shfl_xor(dab, m);
    }
    float inva = 1.0f / fmaxf(sqrtf(ssa), 1e-8f);
    float invb = 1.0f / fmaxf(sqrtf(ssb), 1e-8f);
    float sa = 1.4142135623730951f * inva;
    float sb = 1.4142135623730951f * invb;
    int pa = __builtin_amdgcn_cvt_pk_fp8_f32(a.x * sa, a.y * sa, 0, false);
    pa     = __builtin_amdgcn_cvt_pk_fp8_f32(a.z * sa, a.w * sa, pa, true);
    int pb = __builtin_amdgcn_cvt_pk_fp8_f32(b.x * sb, b.y * sb, 0, false);
    pb     = __builtin_amdgcn_cvt_pk_fp8_f32(b.z * sb, b.w * sb, pb, true);
    // lane's 4 bytes are orig k = 4*lane..+3: ks = lane>>3, kgrp = (lane>>1)&3,
    // inner dword = lane&1  ->  permuted dword offset:
    int p = ((lane >> 1) & 3) * 64 + (lane >> 3) * 8 + (lane & 1) * 4;
    *reinterpret_cast<int*>(zn8 + (size_t)i * D_DIM + p)            = pa;
    *reinterpret_cast<int*>(zn8 + (size_t)(i + B_HALF) * D_DIM + p) = pb;
    if (lane == 0) {
        float pp = 2.0f * dab * inva * invb;
        pos[i]          = pp;
        pos[i + B_HALF] = pp;
    }
}

// ---------------------------------------------------------------------------
// Kernel 2: fused rowsum_i += sum_j exp(s_ij - 2), diag excluded.  FP8 MFMA.
// BM=256 A strip staged once -> LDS -> ALL 16 A-fragments hoisted to REGISTERS
// (64 VGPR), so the steady-state K-loop reads ONLY B from LDS (halves the
// LDS-read floor).  B: 128-col full-K tiles, DOUBLE-buffered (2x32 KB);
// stage(t+1) issued BEFORE tile t's MFMA phase -> full-iteration latency
// cover, barrier drain ~free (T3-minimum schedule).
// 512 thr = 8 waves (4x2), wave = 64x64 out (4x4 frags).  Grid (32,8) = 256
// blocks = exactly 1/CU, 2 waves/SIMD.  LDS 130 KB (R5 proved >64KB static ok).
// Swizzle (both-sides): cell c of row r at c^(r&15); consecutive 8 lanes
// cover 8 distinct b128 bank-clusters -> conflict-free.
// ---------------------------------------------------------------------------
__global__ __launch_bounds__(512, 2) void simexp_kernel(const unsigned char* __restrict__ zn8,
                                                        float* __restrict__ partials) {
    __shared__ __attribute__((aligned(16))) unsigned char lA[BM * D_DIM];       // 64 KB
    __shared__ __attribute__((aligned(16))) unsigned char lB[2][128 * D_DIM];   // 64 KB
    __shared__ float red[8][64];                                                // 2 KB

    const int bi = blockIdx.x;            // row strip of 256 (0..31)
    const int ci = blockIdx.y;            // col split (0..7)
    const int tid  = threadIdx.x;         // 0..511
    const int lane = tid & 63;
    const int wid  = tid >> 6;            // 0..7
    const int wr   = wid >> 1;            // wave row 0..3 (64 rows each)
    const int wc   = wid & 1;             // wave col 0..1 (64 cols each)
    const int lrow16 = lane & 15;
    const int kgrp   = lane >> 4;         // 0..3

    const unsigned char* Abase  = zn8 + (size_t)bi * BM * D_DIM;
    const unsigned char* Bbase0 = zn8 + (size_t)ci * COLS_PER_SPLIT * D_DIM;

    // staging source offsets (swizzled): granule (r, c) <- src cell c^(r&15)
    int soffA[8], soffB[4];
#pragma unroll
    for (int u = 0; u < 8; ++u) {
        const int g = tid + u * 512;      // A: 4096 granules (256 rows)
        const int r = g >> 4, c = g & 15;
        soffA[u] = r * D_DIM + ((c ^ (r & 15)) << 4);
    }
#pragma unroll
    for (int u = 0; u < 4; ++u) {
        const int g = tid + u * 512;      // B: 2048 granules (128 rows)
        const int r = g >> 4, c = g & 15;
        soffB[u] = r * D_DIM + ((c ^ (r & 15)) << 4);
    }

    auto stageB = [&](int t, int buf) {
        const unsigned char* Bb = Bbase0 + (size_t)t * 128 * D_DIM;
#pragma unroll
        for (int u = 0; u < 4; ++u)
            GLOAD16(Bb + soffB[u], lB[buf] + ((tid + u * 512) << 4));
    };

    // ---- prologue: stage A (once) + B0 ----
#pragma unroll
    for (int u = 0; u < 8; ++u)
        GLOAD16(Abase + soffA[u], lA + ((tid + u * 512) << 4));
    stageB(0, 0);
    __syncthreads();                      // A + B0 landed (vmcnt drained)

    // ---- hoist all A fragments to registers: aF[ks2][mt], 64 VGPR ----
    long2_t aF[4][4];
#pragma unroll
    for (int ks2 = 0; ks2 < 4; ++ks2)
#pragma unroll
        for (int mt = 0; mt < 4; ++mt)
            aF[ks2][mt] = *reinterpret_cast<const long2_t*>(
                lA + (wr * 64 + mt * 16 + lrow16) * D_DIM
                   + (((kgrp * 4 + ks2) ^ lrow16) << 4));

    float rowacc[4][4];
#pragma unroll
    for (int mt = 0; mt < 4; ++mt)
#pragma unroll
        for (int r = 0; r < 4; ++r) rowacc[mt][r] = 0.0f;

    for (int t = 0; t < NTILE; ++t) {
        if (t + 1 < NTILE) stageB(t + 1, (t + 1) & 1);   // issue FIRST (dbuf)
        const unsigned char* Bl = lB[t & 1];

        f32x4 acc[4][4];
#pragma unroll
        for (int mt = 0; mt < 4; ++mt)
#pragma unroll
            for (int nt = 0; nt < 4; ++nt) acc[mt][nt] = (f32x4)(0.0f);

#pragma unroll
        for (int ks2 = 0; ks2 < 4; ++ks2) {
            long2_t bF[4];
#pragma unroll
            for (int nt = 0; nt < 4; ++nt)
                bF[nt] = *reinterpret_cast<const long2_t*>(
                    Bl + (wc * 64 + nt * 16 + lrow16) * D_DIM
                       + (((kgrp * 4 + ks2) ^ lrow16) << 4));
#pragma unroll
            for (int mt = 0; mt < 4; ++mt)
#pragma unroll
                for (int nt = 0; nt < 4; ++nt) {
                    acc[mt][nt] = __builtin_amdgcn_mfma_f32_16x16x32_fp8_fp8(
                        aF[ks2][mt][0], bF[nt][0], acc[mt][nt], 0, 0, 0);
                    acc[mt][nt] = __builtin_amdgcn_mfma_f32_16x16x32_fp8_fp8(
                        aF[ks2][mt][1], bF[nt][1], acc[mt][nt], 0, 0, 0);
                }
        }

        // ---- register-only exp epilogue (covers the in-flight B stage) ----
        const int cb  = ci * NTILE + t;        // global 128-col block index
        const bool dg = (cb >> 1) == bi;       // tile intersects the diagonal
        const int sub = (cb & 1) << 7;         // 0 or 128: which row half
        if (dg) {
#pragma unroll
            for (int mt = 0; mt < 4; ++mt) {
                const int lrowb = wr * 64 + mt * 16 + 4 * kgrp - sub;
#pragma unroll
                for (int r = 0; r < 4; ++r) {
                    const int lrow = lrowb + r;
                    float s = 0.0f;
#pragma unroll
                    for (int nt = 0; nt < 4; ++nt) {
                        const int lcol = wc * 64 + nt * 16 + lrow16;
                        float e = __expf(acc[mt][nt][r] - 2.0f);
                        s += (lrow == lcol) ? 0.0f : e;
                    }
                    rowacc[mt][r] += s;
                }
            }
        } else {
#pragma unroll
            for (int mt = 0; mt < 4; ++mt)
#pragma unroll
                for (int r = 0; r < 4; ++r) {
                    float s = 0.0f;
#pragma unroll
                    for (int nt = 0; nt < 4; ++nt)
                        s += __expf(acc[mt][nt][r] - 2.0f);
                    rowacc[mt][r] += s;
                }
        }
        __syncthreads();                   // B(t+1) landed; all reads of buf done
    }

    // ---- block-end reduce across the 16 col-lanes ----
#pragma unroll
    for (int mt = 0; mt < 4; ++mt)
#pragma unroll
        for (int r = 0; r < 4; ++r) {
            float v = rowacc[mt][r];
            v += __shfl_xor(v, 1); v += __shfl_xor(v, 2);
            v += __shfl_xor(v, 4); v += __shfl_xor(v, 8);
            if (lrow16 == 0) red[wid][mt * 16 + kgrp * 4 + r] = v;
        }
    __syncthreads();
    if (tid < BM) {                        // 256 rows; wc pairs combine
        const int wrr = tid >> 6, l = tid & 63;
        partials[(size_t)ci * N_TOTAL + bi * BM + tid] =
            red[wrr * 2][l] + red[wrr * 2 + 1][l];
    }
}

// ---------------------------------------------------------------------------
// Kernel 3: per-row lse - pos, block-partial sums (deterministic).
// ---------------------------------------------------------------------------
__global__ __launch_bounds__(256) void lse_kernel(const float* __restrict__ partials,
                                                  const float* __restrict__ pos,
                                                  float* __restrict__ bsums) {
    int tid = threadIdx.x;
    int row = blockIdx.x * 256 + tid;
    float s = 0.0f;
#pragma unroll
    for (int c = 0; c < CSPLIT; ++c) s += partials[(size_t)c * N_TOTAL + row];
    float v = 2.0f + logf(s) - pos[row];
#pragma unroll
    for (int m = 32; m >= 1; m >>= 1) v += __shfl_xor(v, m);
    __shared__ float wsum[4];
    if ((tid & 63) == 0) wsum[tid >> 6] = v;
    __syncthreads();
    if (tid == 0) bsums[blockIdx.x] = wsum[0] + wsum[1] + wsum[2] + wsum[3];
}

__global__ void final_kernel(const float* __restrict__ bsums, float* __restrict__ out) {
    int tid = threadIdx.x;                // 64 threads
    float v = (tid < N_TOTAL / 256) ? bsums[tid] : 0.0f;
#pragma unroll
    for (int m = 32; m >= 1; m >>= 1) v += __shfl_xor(v, m);
    if (tid == 0) out[0] = v * (1.0f / (float)N_TOTAL);
}

// ---------------------------------------------------------------------------
extern "C" void kernel_launch(void* const* d_in, const int* in_sizes, int n_in,
                              void* d_out, int out_size, void* d_ws, size_t ws_size,
                              hipStream_t stream) {
    const float* z1 = (const float*)d_in[0];
    const float* z2 = (const float*)d_in[1];
    float* out = (float*)d_out;

    char* ws = (char*)d_ws;
    unsigned char* zn8 = (unsigned char*)ws;                               // 2 MB
    size_t off = (size_t)N_TOTAL * D_DIM;
    float* pos = (float*)(ws + off);                                       // 32 KB
    off += (size_t)N_TOTAL * sizeof(float);
    float* partials = (float*)(ws + off);                                  // 256 KB
    off += (size_t)CSPLIT * N_TOTAL * sizeof(float);
    float* bsums = (float*)(ws + off);                                     // 128 B

    nrmpos_kernel<<<B_HALF / 4, 256, 0, stream>>>(z1, z2, zn8, pos);
    simexp_kernel<<<dim3(N_TOTAL / BM, CSPLIT), 512, 0, stream>>>(zn8, partials);
    lse_kernel<<<N_TOTAL / 256, 256, 0, stream>>>(partials, pos, bsums);
    final_kernel<<<1, 64, 0, stream>>>(bsums, out);
}